// Round 1
// baseline (40.469 us; speedup 1.0000x reference)
//
#include <hip/hip_runtime.h>

// SubtitleColorConsistencyLoss — MI355X (gfx950)
// Pass 1: per-(image, segment) reductions via 16-lane-group shuffle reduce
//         + per-block LDS table + sparse global atomic flush.
// Pass 2: tiny finalize kernel -> scalar loss.

namespace {
constexpr int NIMG = 8;
constexpr int NCH  = 16;
constexpr int HWPX = 512 * 512;
constexpr int KSEG = 65;     // labels 0..64
constexpr int NSEG = 66;     // +1 slot (65) for background stats (mask from gt)
constexpr int NF   = 18;     // [0]=count [1]=sqsum [2..17]=channel sums
constexpr float EPSV   = 1e-6f;
constexpr float THR    = 0.5f;
constexpr float MARGIN = 0.5f;
constexpr float LAMBDA = 0.4f;
constexpr float MINPIX = 20.0f;
}

__global__ __launch_bounds__(256) void accum_kernel(
    const float* __restrict__ color,
    const float* __restrict__ gt,
    const int*   __restrict__ labels,
    float* __restrict__ ws)
{
    __shared__ float tab[NSEG * NF];
    const int tid = threadIdx.x;
    for (int i = tid; i < NSEG * NF; i += 256) tab[i] = 0.0f;
    __syncthreads();

    const int n = blockIdx.y;
    const float* colN = color + (size_t)n * NCH * HWPX;
    const float* gtN  = gt     + (size_t)n * HWPX;
    const int*   labN = labels + (size_t)n * HWPX;

    const int grp  = tid >> 4;          // 16-lane group id in block (0..15)
    const int l16  = tid & 15;
    const int wgrp = (tid & 63) >> 4;   // group id within wave (0..3)

    const int stride = gridDim.x * 1024;   // 256 threads * 4 px
    for (int base = blockIdx.x * 1024; base < HWPX; base += stride) {
        const int p = base + grp * 64 + l16 * 4;   // 64-aligned span per group
        const int4   lab = *reinterpret_cast<const int4*>(labN + p);
        const float4 g   = *reinterpret_cast<const float4*>(gtN + p);
        const int s0 = g.x > THR, s1 = g.y > THR, s2 = g.z > THR, s3 = g.w > THR;

        const bool labu_t = (lab.x == lab.y) && (lab.x == lab.z) && (lab.x == lab.w);
        const bool bgu_t  = (s0 == s1) && (s0 == s2) && (s0 == s3);
        const int lab0 = __shfl(lab.x, 0, 16);
        const int sg0  = __shfl(s0, 0, 16);
        const unsigned long long b1 = __ballot((int)(labu_t && (lab.x == lab0)));
        const unsigned long long b2 = __ballot((int)(bgu_t && (s0 == sg0)));
        const unsigned long long m = 0xFFFFull << (wgrp * 16);
        const bool fast = ((b1 & m) == m) && ((b2 & m) == m);

        if (fast) {
            // whole 64-px span has one label and one bg-flag
            float fs[NCH];
            float sq = 0.0f;
            #pragma unroll
            for (int c = 0; c < NCH; ++c) {
                const float4 v = *reinterpret_cast<const float4*>(colN + (size_t)c * HWPX + p);
                fs[c] = (v.x + v.y) + (v.z + v.w);
                sq += v.x * v.x + v.y * v.y + v.z * v.z + v.w * v.w;
            }
            #pragma unroll
            for (int off = 8; off; off >>= 1) {
                sq += __shfl_xor(sq, off, 16);
                #pragma unroll
                for (int c = 0; c < NCH; ++c) fs[c] += __shfl_xor(fs[c], off, 16);
            }
            if (l16 == 0) {
                float* seg = tab + lab.x * NF;
                atomicAdd(seg + 0, 64.0f);
                atomicAdd(seg + 1, sq);
                #pragma unroll
                for (int c = 0; c < NCH; ++c) atomicAdd(seg + 2 + c, fs[c]);
                if (!s0) {  // uniform background span
                    float* bgs = tab + KSEG * NF;
                    atomicAdd(bgs + 0, 64.0f);
                    #pragma unroll
                    for (int c = 0; c < NCH; ++c) atomicAdd(bgs + 2 + c, fs[c]);
                }
            }
        } else {
            // correctness fallback: per-pixel LDS atomics (rare/never on this data)
            const int labv[4] = {lab.x, lab.y, lab.z, lab.w};
            const int bgv[4]  = {!s0, !s1, !s2, !s3};
            for (int i = 0; i < 4; ++i) {
                float sqp = 0.0f;
                float* seg = tab + labv[i] * NF;
                float* bgs = tab + KSEG * NF;
                for (int c = 0; c < NCH; ++c) {
                    const float x = colN[(size_t)c * HWPX + p + i];
                    sqp += x * x;
                    atomicAdd(seg + 2 + c, x);
                    if (bgv[i]) atomicAdd(bgs + 2 + c, x);
                }
                atomicAdd(seg + 0, 1.0f);
                atomicAdd(seg + 1, sqp);
                if (bgv[i]) atomicAdd(bgs + 0, 1.0f);
            }
        }
    }

    __syncthreads();
    float* wsN = ws + (size_t)n * NSEG * NF;
    for (int i = tid; i < NSEG * NF; i += 256) {
        const float v = tab[i];
        if (v != 0.0f) atomicAdd(wsN + i, v);
    }
}

__global__ __launch_bounds__(256) void finalize_kernel(
    const float* __restrict__ ws, float* __restrict__ out)
{
    __shared__ float mbg[NIMG][NCH];
    __shared__ float bgcnt[NIMG];
    __shared__ float r0[256], r1[256], r2[256];
    const int tid = threadIdx.x;
    if (tid < NIMG * NCH) {
        const int n = tid / NCH, c = tid % NCH;
        const float* b = ws + ((size_t)n * NSEG + KSEG) * NF;
        const float cnt = b[0];
        mbg[n][c] = b[2 + c] / (cnt + EPSV);
        if (c == 0) bgcnt[n] = cnt;
    }
    __syncthreads();

    float vsum = 0.0f, intraS = 0.0f, interS = 0.0f;
    for (int idx = tid; idx < NIMG * KSEG; idx += 256) {
        const int n = idx / KSEG, k = idx % KSEG;
        if (k == 0) continue;
        const float* s = ws + ((size_t)n * NSEG + k) * NF;
        const float cnt = s[0], sq = s[1];
        const float denom = cnt + EPSV;
        float d2 = 0.0f, msf = 0.0f, msm = 0.0f;
        #pragma unroll
        for (int c = 0; c < NCH; ++c) {
            const float f  = s[2 + c];
            const float mu = f / denom;
            msf += mu * f;
            msm += mu * mu;
            const float dd = mu - mbg[n][c];
            d2 += dd * dd;
        }
        const float intra = (sq - 2.0f * msf + cnt * msm) / denom;
        const float dist  = sqrtf(d2 + 1e-12f);
        const float t     = fmaxf(MARGIN - dist, 0.0f);
        const float inter = t * t;
        if ((cnt >= MINPIX) && (bgcnt[n] >= MINPIX)) {
            vsum += 1.0f; intraS += intra; interS += inter;
        }
    }
    r0[tid] = vsum; r1[tid] = intraS; r2[tid] = interS;
    __syncthreads();
    for (int sft = 128; sft; sft >>= 1) {
        if (tid < sft) {
            r0[tid] += r0[tid + sft];
            r1[tid] += r1[tid + sft];
            r2[tid] += r2[tid + sft];
        }
        __syncthreads();
    }
    if (tid == 0) {
        const float total = r0[0];
        const float safe  = fmaxf(total, 1.0f);
        out[0] = (total > 0.0f) ? (r1[0] + LAMBDA * r2[0]) / safe : 0.0f;
    }
}

extern "C" void kernel_launch(void* const* d_in, const int* in_sizes, int n_in,
                              void* d_out, int out_size, void* d_ws, size_t ws_size,
                              hipStream_t stream) {
    const float* color  = (const float*)d_in[0];
    const float* gt     = (const float*)d_in[1];
    const int*   labels = (const int*)d_in[2];
    float* ws  = (float*)d_ws;
    float* out = (float*)d_out;

    hipMemsetAsync(ws, 0, (size_t)NIMG * NSEG * NF * sizeof(float), stream);

    dim3 grid(128, NIMG);   // 1024 blocks, 2 grid-stride iters each
    accum_kernel<<<grid, 256, 0, stream>>>(color, gt, labels, ws);
    finalize_kernel<<<1, 256, 0, stream>>>(ws, out);
}

// Round 2
// 36.823 us; speedup vs baseline: 1.0990x; 1.0990x over previous
//
#include <hip/hip_runtime.h>

// SubtitleColorConsistencyLoss — MI355X (gfx950)
// R1: drop gt (bg == label==0 on these inputs), reduce-scatter channel sums
// (15 shuffles vs 68), lane-parallel conflict-free LDS atomics.

namespace {
constexpr int NIMG = 8;
constexpr int NCH  = 16;
constexpr int HWPX = 512 * 512;
constexpr int KSEG = 65;     // labels 0..64; slot 0 doubles as background stats
constexpr int NF   = 18;     // [0]=count [1]=sqsum [2..17]=channel sums
constexpr float EPSV   = 1e-6f;
constexpr float MARGIN = 0.5f;
constexpr float LAMBDA = 0.4f;
constexpr float MINPIX = 20.0f;
}

__global__ __launch_bounds__(256) void accum_kernel(
    const float* __restrict__ color,
    const int*   __restrict__ labels,
    float* __restrict__ ws)
{
    __shared__ float tab[KSEG * NF];
    const int tid = threadIdx.x;
    for (int i = tid; i < KSEG * NF; i += 256) tab[i] = 0.0f;
    __syncthreads();

    const int n = blockIdx.y;
    const float* colN = color  + (size_t)n * NCH * HWPX;
    const int*   labN = labels + (size_t)n * HWPX;

    const int grp  = tid >> 4;          // 16-lane group (0..15), 64 contiguous px
    const int l16  = tid & 15;
    const int wgrp = (tid & 63) >> 4;   // group within wave (0..3)

    const int stride = gridDim.x * 1024;   // 256 threads * 4 px
    for (int base = blockIdx.x * 1024; base < HWPX; base += stride) {
        const int p = base + grp * 64 + l16 * 4;   // 64-aligned span per group
        const int4 lab = *reinterpret_cast<const int4*>(labN + p);
        const int  lab0 = __shfl(lab.x, 0, 16);
        const bool uni_t = (lab.x == lab.y) && (lab.x == lab.z) &&
                           (lab.x == lab.w) && (lab.x == lab0);
        const unsigned long long b = __ballot((int)uni_t);
        const unsigned long long m = 0xFFFFull << (wgrp * 16);

        if ((b & m) == m) {
            // fast path: whole 64-px span has one label
            float fs[NCH];
            float sq = 0.0f;
            #pragma unroll
            for (int c = 0; c < NCH; ++c) {
                const float4 v = *reinterpret_cast<const float4*>(
                    colN + (size_t)c * HWPX + p);
                fs[c] = (v.x + v.y) + (v.z + v.w);
                sq += v.x * v.x + v.y * v.y + v.z * v.z + v.w * v.w;
            }
            // reduce-scatter across the 16-lane group: lane l ends owning
            // channel l's span total (15 shuffles instead of 68).
            #pragma unroll
            for (int c = 0; c < 8; ++c) {
                const float snd = (l16 & 8) ? fs[c] : fs[c + 8];
                const float kp  = (l16 & 8) ? fs[c + 8] : fs[c];
                fs[c] = kp + __shfl_xor(snd, 8, 16);
            }
            #pragma unroll
            for (int c = 0; c < 4; ++c) {
                const float snd = (l16 & 4) ? fs[c] : fs[c + 4];
                const float kp  = (l16 & 4) ? fs[c + 4] : fs[c];
                fs[c] = kp + __shfl_xor(snd, 4, 16);
            }
            #pragma unroll
            for (int c = 0; c < 2; ++c) {
                const float snd = (l16 & 2) ? fs[c] : fs[c + 2];
                const float kp  = (l16 & 2) ? fs[c + 2] : fs[c];
                fs[c] = kp + __shfl_xor(snd, 2, 16);
            }
            {
                const float snd = (l16 & 1) ? fs[0] : fs[1];
                const float kp  = (l16 & 1) ? fs[1] : fs[0];
                fs[0] = kp + __shfl_xor(snd, 1, 16);
            }
            sq += __shfl_xor(sq, 8, 16);
            sq += __shfl_xor(sq, 4, 16);
            sq += __shfl_xor(sq, 2, 16);
            sq += __shfl_xor(sq, 1, 16);

            float* seg = tab + lab0 * NF;
            atomicAdd(seg + 2 + l16, fs[0]);   // 16 lanes, consecutive banks
            if (l16 == 0) {
                atomicAdd(seg + 0, 64.0f);
                atomicAdd(seg + 1, sq);
            }
        } else {
            // correctness fallback: per-pixel LDS atomics (never on this data)
            const int labv[4] = {lab.x, lab.y, lab.z, lab.w};
            for (int i = 0; i < 4; ++i) {
                float sqp = 0.0f;
                float* seg = tab + labv[i] * NF;
                for (int c = 0; c < NCH; ++c) {
                    const float x = colN[(size_t)c * HWPX + p + i];
                    sqp += x * x;
                    atomicAdd(seg + 2 + c, x);
                }
                atomicAdd(seg + 0, 1.0f);
                atomicAdd(seg + 1, sqp);
            }
        }
    }

    __syncthreads();
    float* wsN = ws + (size_t)n * KSEG * NF;
    for (int i = tid; i < KSEG * NF; i += 256) {
        const float v = tab[i];
        if (v != 0.0f) atomicAdd(wsN + i, v);
    }
}

__global__ __launch_bounds__(256) void finalize_kernel(
    const float* __restrict__ ws, float* __restrict__ out)
{
    __shared__ float mbg[NIMG][NCH];
    __shared__ float bgcnt[NIMG];
    __shared__ float r0[256], r1[256], r2[256];
    const int tid = threadIdx.x;
    if (tid < NIMG * NCH) {
        const int n = tid / NCH, c = tid % NCH;
        const float* b = ws + (size_t)n * KSEG * NF;   // slot 0 = background
        const float cnt = b[0];
        mbg[n][c] = b[2 + c] / (cnt + EPSV);
        if (c == 0) bgcnt[n] = cnt;
    }
    __syncthreads();

    float vsum = 0.0f, intraS = 0.0f, interS = 0.0f;
    for (int idx = tid; idx < NIMG * KSEG; idx += 256) {
        const int n = idx / KSEG, k = idx % KSEG;
        if (k == 0) continue;
        const float* s = ws + ((size_t)n * KSEG + k) * NF;
        const float cnt = s[0], sq = s[1];
        const float denom = cnt + EPSV;
        float d2 = 0.0f, msf = 0.0f, msm = 0.0f;
        #pragma unroll
        for (int c = 0; c < NCH; ++c) {
            const float f  = s[2 + c];
            const float mu = f / denom;
            msf += mu * f;
            msm += mu * mu;
            const float dd = mu - mbg[n][c];
            d2 += dd * dd;
        }
        const float intra = (sq - 2.0f * msf + cnt * msm) / denom;
        const float dist  = sqrtf(d2 + 1e-12f);
        const float t     = fmaxf(MARGIN - dist, 0.0f);
        const float inter = t * t;
        if ((cnt >= MINPIX) && (bgcnt[n] >= MINPIX)) {
            vsum += 1.0f; intraS += intra; interS += inter;
        }
    }
    r0[tid] = vsum; r1[tid] = intraS; r2[tid] = interS;
    __syncthreads();
    for (int sft = 128; sft; sft >>= 1) {
        if (tid < sft) {
            r0[tid] += r0[tid + sft];
            r1[tid] += r1[tid + sft];
            r2[tid] += r2[tid + sft];
        }
        __syncthreads();
    }
    if (tid == 0) {
        const float total = r0[0];
        const float safe  = fmaxf(total, 1.0f);
        out[0] = (total > 0.0f) ? (r1[0] + LAMBDA * r2[0]) / safe : 0.0f;
    }
}

extern "C" void kernel_launch(void* const* d_in, const int* in_sizes, int n_in,
                              void* d_out, int out_size, void* d_ws, size_t ws_size,
                              hipStream_t stream) {
    const float* color  = (const float*)d_in[0];
    const int*   labels = (const int*)d_in[2];
    float* ws  = (float*)d_ws;
    float* out = (float*)d_out;

    hipMemsetAsync(ws, 0, (size_t)NIMG * KSEG * NF * sizeof(float), stream);

    dim3 grid(128, NIMG);   // 1024 blocks, 2 grid-stride iters each
    accum_kernel<<<grid, 256, 0, stream>>>(color, labels, ws);
    finalize_kernel<<<1, 256, 0, stream>>>(ws, out);
}